// Round 2
// baseline (478.285 us; speedup 1.0000x reference)
//
#include <hip/hip_runtime.h>

// ---------------------------------------------------------------------------
// Kernel 0: repack conv2/conv3 weights into [ic*9+tap][oc] linear layout.
// UNCHANGED.
// ---------------------------------------------------------------------------
__global__ __launch_bounds__(256) void repack_kernel(
    const float* __restrict__ cw2, const float* __restrict__ cw3,
    float* __restrict__ packed2, float* __restrict__ packed3)
{
    int t = blockIdx.x * 256 + threadIdx.x;   // grid 72*256 = 18432 = 2*9216
    if (t < 9216) {
        int oc = t & 31, r = t >> 5;          // r = ic*9+tap in [0,288)
        packed2[t] = cw2[oc * 288 + r];
    } else {
        int t2 = t - 9216;
        int oc = t2 & 31, r = t2 >> 5;
        packed3[t2] = cw3[oc * 288 + r];
    }
}

// ---------------------------------------------------------------------------
// Kernel 1: fused conv stack (r12 structure: 38.4 KB LDS, ~4 blocks/CU, ~82%
// VALUBusy) + fused BatchNorm partial-sum epilogue -> gstats[64] atomics.
// UNCHANGED (312 us, the measured winner) — this round targets the MLP tail.
// ---------------------------------------------------------------------------
__global__ __launch_bounds__(256)
void fused_conv_kernel(
    const float* __restrict__ x,
    const float* __restrict__ cw1, const float* __restrict__ cb1,
    const float* __restrict__ packed2, const float* __restrict__ cb2,
    const float* __restrict__ packed3, const float* __restrict__ cb3,
    float* __restrict__ out3, float* __restrict__ gstats)
{
    const int img = blockIdx.x;
    const int tid = threadIdx.x;

    __shared__ float A[1220];         // xs1(900)+w1s(288)+b1s(32) | wck2(1152)
    __shared__ float B[8320];         // xs2 (32 x 260) | scratch/xs3/wck3
    __shared__ float b2s[32], b3s[32];

    float* xs1  = A;                  // 900: 30x30 padded image
    float* w1s  = A + 900;            // 288
    float* b1s  = A + 1188;           // 32
    float* wck2 = A;                  // 1152: conv2 4-ic chunk (after conv1)
    float* xs2  = B;                  // 32 planes x 260
    float* sc   = B;                  // reduction scratch head
    float* xs3  = B + 1280;           // 2880: 32 x 90 -> [1280,4160)
    float* wck3 = B + 4160;           // 2304: conv3 8-ic chunk -> [4160,6464)
    float* sc2  = B + 5073;           // pool scratch -> [5102,8320)

    // --- zero xs1 pads + all of B ---
    for (int i = tid; i < 900;  i += 256) xs1[i] = 0.f;
    for (int i = tid; i < 8320; i += 256) B[i] = 0.f;
    __syncthreads();

    // --- stage input image + conv1 weights + biases ---
    for (int i = tid; i < 784; i += 256) {
        int yy = i / 28, xx = i % 28;
        xs1[(yy + 1) * 30 + xx + 1] = x[img * 784 + i];
    }
    for (int i = tid; i < 288; i += 256) {
        int oc = i & 31, tap = i >> 5;
        w1s[i] = cw1[oc * 9 + tap];
    }
    if (tid < 32) { b1s[tid] = cb1[tid]; b2s[tid] = cb2[tid]; b3s[tid] = cb3[tid]; }
    __syncthreads();

    // --- conv1 (1->32) + relu + pool -> xs2 (swizzled) ---
    {
        const int c1 = tid & 31;
        float w1r[9];
        #pragma unroll
        for (int t = 0; t < 9; t++) w1r[t] = w1s[t * 32 + c1];
        const float bias1 = b1s[c1];
        for (int o = tid; o < 32 * 196; o += 256) {
            int p = o >> 5;
            int py = p / 14, px = p % 14;
            int base = (2 * py) * 30 + 2 * px;
            float P[16];
            #pragma unroll
            for (int r = 0; r < 4; r++) {
                float2 u0 = *(const float2*)&xs1[base + r * 30];
                float2 u1 = *(const float2*)&xs1[base + r * 30 + 2];
                P[r * 4 + 0] = u0.x; P[r * 4 + 1] = u0.y;
                P[r * 4 + 2] = u1.x; P[r * 4 + 3] = u1.y;
            }
            float a00 = 0.f, a01 = 0.f, a10 = 0.f, a11 = 0.f;
            #pragma unroll
            for (int ky = 0; ky < 3; ky++)
                #pragma unroll
                for (int kx = 0; kx < 3; kx++) {
                    float w = w1r[ky * 3 + kx];
                    a00 = fmaf(P[ky * 4 + kx],           w, a00);
                    a01 = fmaf(P[ky * 4 + kx + 1],       w, a01);
                    a10 = fmaf(P[(ky + 1) * 4 + kx],     w, a10);
                    a11 = fmaf(P[(ky + 1) * 4 + kx + 1], w, a11);
                }
            float v = fmaxf(fmaxf(fmaxf(a00, a01), fmaxf(a10, a11)) + bias1, 0.f);
            int r = py + 1, col = px + 1;
            xs2[c1 * 260 + r * 16 + ((((col >> 2) + r) & 3) << 2) + (col & 3)] = v;
        }
    }

    // --- conv2: 4oc x 14 cols, K-split-2 over 8 chunks of 4 ic ---
    const int g  = tid >> 7;            // K-group 0..1 (2 waves each)
    const int u  = tid & 127;           // unit; active if u < 112
    const int cb = u & 7, R = u >> 3;   // oc-quad, prepool row 0..13
    const int oc0 = cb * 4;
    const bool act2 = (u < 112);

    float acc[4][14];
    #pragma unroll
    for (int a = 0; a < 4; a++)
        #pragma unroll
        for (int c = 0; c < 14; c++) acc[a][c] = 0.f;

    float pf[5];                        // 1152 = 4.5*256
    #pragma unroll
    for (int k = 0; k < 5; k++) {
        int idx = tid + k * 256;
        pf[k] = (idx < 1152) ? packed2[idx] : 0.f;
    }

    for (int ch = 0; ch < 8; ch++) {
        __syncthreads();                // conv1/xs2 writes + prior wck2 reads done
        #pragma unroll
        for (int k = 0; k < 5; k++) {
            int idx = tid + k * 256;
            if (idx < 1152) wck2[idx] = pf[k];
        }
        if (ch < 7) {
            #pragma unroll
            for (int k = 0; k < 5; k++) {
                int idx = tid + k * 256;
                pf[k] = (idx < 1152) ? packed2[(ch + 1) * 1152 + idx] : 0.f;
            }
        }
        __syncthreads();
        if (act2) {
            #pragma unroll
            for (int d = 0; d < 2; d++) {
                const int ld = g * 2 + d;            // local ic 0..3
                const int ic = ch * 4 + ld;
                const float* wd = &wck2[ld * 288 + oc0];
                const int pb = ic * 260;
                #pragma unroll
                for (int ky = 0; ky < 3; ky++) {
                    const int rp = R + ky;
                    const int rb = pb + rp * 16;
                    float row[16];
                    #pragma unroll
                    for (int q = 0; q < 4; q++) {
                        const float4 t = *(const float4*)&xs2[rb + (((q + rp) & 3) << 2)];
                        row[q * 4 + 0] = t.x; row[q * 4 + 1] = t.y;
                        row[q * 4 + 2] = t.z; row[q * 4 + 3] = t.w;
                    }
                    const float4 wa = *(const float4*)&wd[(ky * 3 + 0) * 32];
                    const float4 wb = *(const float4*)&wd[(ky * 3 + 1) * 32];
                    const float4 wc = *(const float4*)&wd[(ky * 3 + 2) * 32];
                    #pragma unroll
                    for (int c = 0; c < 14; c++) {
                        acc[0][c] = fmaf(row[c],     wa.x, acc[0][c]);
                        acc[1][c] = fmaf(row[c],     wa.y, acc[1][c]);
                        acc[2][c] = fmaf(row[c],     wa.z, acc[2][c]);
                        acc[3][c] = fmaf(row[c],     wa.w, acc[3][c]);
                        acc[0][c] = fmaf(row[c + 1], wb.x, acc[0][c]);
                        acc[1][c] = fmaf(row[c + 1], wb.y, acc[1][c]);
                        acc[2][c] = fmaf(row[c + 1], wb.z, acc[2][c]);
                        acc[3][c] = fmaf(row[c + 1], wb.w, acc[3][c]);
                        acc[0][c] = fmaf(row[c + 2], wc.x, acc[0][c]);
                        acc[1][c] = fmaf(row[c + 2], wc.y, acc[1][c]);
                        acc[2][c] = fmaf(row[c + 2], wc.z, acc[2][c]);
                        acc[3][c] = fmaf(row[c + 2], wc.w, acc[3][c]);
                    }
                }
            }
        }
    }

    // --- conv2 K-reduction (1 round, stride-57 scratch in B head, max 6382) ---
    __syncthreads();                     // all xs2 patch reads done
    if (g == 1 && act2) {
        #pragma unroll
        for (int a = 0; a < 4; a++)
            #pragma unroll
            for (int c = 0; c < 14; c++) sc[u * 57 + a * 14 + c] = acc[a][c];
    }
    __syncthreads();
    if (g == 0 && act2) {
        #pragma unroll
        for (int a = 0; a < 4; a++)
            #pragma unroll
            for (int c = 0; c < 14; c++) acc[a][c] += sc[u * 57 + a * 14 + c];
    }
    __syncthreads();                     // reduction scratch retires

    // --- zero xs3 + pool 14x14->7x7 (register hmax, odd/even R via sc2) ---
    for (int i = tid; i < 2880; i += 256) xs3[i] = 0.f;
    float hm[4][7];
    if (g == 0 && act2) {
        #pragma unroll
        for (int a = 0; a < 4; a++)
            #pragma unroll
            for (int c = 0; c < 7; c++)
                hm[a][c] = fmaxf(acc[a][2 * c], acc[a][2 * c + 1]);
        if (R & 1) {                     // sc2 idx max 111*29+27=3246 -> abs 8319
            #pragma unroll
            for (int a = 0; a < 4; a++)
                #pragma unroll
                for (int c = 0; c < 7; c++) sc2[u * 29 + a * 7 + c] = hm[a][c];
        }
    }
    __syncthreads();
    if (g == 0 && act2 && !(R & 1)) {
        const int py = R >> 1;           // 0..6
        #pragma unroll
        for (int a = 0; a < 4; a++)
            #pragma unroll
            for (int c = 0; c < 7; c++) {
                float v = fmaxf(hm[a][c], sc2[(u + 8) * 29 + a * 7 + c]);
                v = fmaxf(v + b2s[oc0 + a], 0.f);
                xs3[(oc0 + a) * 90 + (py + 1) * 10 + (c + 1)] = v;
            }
    }

    // --- conv3 (32->32, 7x7) + relu + pool(7->3 floor), K-split-2 ---
    const int u3 = tid & 127;
    const bool act3 = (u3 < 72);
    const int cq3 = u3 & 7, pos = u3 >> 3;   // oc-quad, pooled pos 0..8
    const int oc30 = cq3 * 4;
    const int py3 = pos / 3, px3 = pos % 3;
    const int base3 = (2 * py3) * 10 + 2 * px3;

    float a3[4][4];
    #pragma unroll
    for (int a = 0; a < 4; a++)
        #pragma unroll
        for (int q = 0; q < 4; q++) a3[a][q] = 0.f;

    float pg[9];                        // 2304 = 9*256
    #pragma unroll
    for (int k = 0; k < 9; k++) pg[k] = packed3[tid + k * 256];

    for (int ch = 0; ch < 4; ch++) {
        __syncthreads();                 // pool/xs3 writes + prior wck3 reads done
        #pragma unroll
        for (int k = 0; k < 9; k++) wck3[tid + k * 256] = pg[k];
        if (ch < 3) {
            #pragma unroll
            for (int k = 0; k < 9; k++) pg[k] = packed3[(ch + 1) * 2304 + tid + k * 256];
        }
        __syncthreads();
        if (act3) {
            #pragma unroll 2
            for (int d = 0; d < 4; d++) {
                const int ld = g * 4 + d;
                const int ic = ch * 8 + ld;
                const float* xp = &xs3[ic * 90 + base3];
                float P[16];
                #pragma unroll
                for (int r = 0; r < 4; r++) {
                    float2 u0 = *(const float2*)&xp[r * 10];
                    float2 u1 = *(const float2*)&xp[r * 10 + 2];
                    P[r * 4 + 0] = u0.x; P[r * 4 + 1] = u0.y;
                    P[r * 4 + 2] = u1.x; P[r * 4 + 3] = u1.y;
                }
                const float* wd = &wck3[ld * 288 + oc30];
                #pragma unroll
                for (int tap = 0; tap < 9; tap++) {
                    const int ky = tap / 3, kx = tap % 3;
                    const float4 wv = *(const float4*)&wd[tap * 32];
                    const float x00 = P[ky * 4 + kx];
                    const float x01 = P[ky * 4 + kx + 1];
                    const float x10 = P[(ky + 1) * 4 + kx];
                    const float x11 = P[(ky + 1) * 4 + kx + 1];
                    a3[0][0] = fmaf(x00, wv.x, a3[0][0]); a3[0][1] = fmaf(x01, wv.x, a3[0][1]);
                    a3[0][2] = fmaf(x10, wv.x, a3[0][2]); a3[0][3] = fmaf(x11, wv.x, a3[0][3]);
                    a3[1][0] = fmaf(x00, wv.y, a3[1][0]); a3[1][1] = fmaf(x01, wv.y, a3[1][1]);
                    a3[1][2] = fmaf(x10, wv.y, a3[1][2]); a3[1][3] = fmaf(x11, wv.y, a3[1][3]);
                    a3[2][0] = fmaf(x00, wv.z, a3[2][0]); a3[2][1] = fmaf(x01, wv.z, a3[2][1]);
                    a3[2][2] = fmaf(x10, wv.z, a3[2][2]); a3[2][3] = fmaf(x11, wv.z, a3[2][3]);
                    a3[3][0] = fmaf(x00, wv.w, a3[3][0]); a3[3][1] = fmaf(x01, wv.w, a3[3][1]);
                    a3[3][2] = fmaf(x10, wv.w, a3[3][2]); a3[3][3] = fmaf(x11, wv.w, a3[3][3]);
                }
            }
        }
    }

    // --- conv3 K-reduction (1 round, stride-17 scratch in head, max 1222) ---
    __syncthreads();
    if (g == 1 && act3) {
        #pragma unroll
        for (int a = 0; a < 4; a++)
            #pragma unroll
            for (int q = 0; q < 4; q++) sc[u3 * 17 + a * 4 + q] = a3[a][q];
    }
    __syncthreads();
    float rres[4];
    const bool writer = (g == 0 && act3);
    if (writer) {
        #pragma unroll
        for (int a = 0; a < 4; a++)
            #pragma unroll
            for (int q = 0; q < 4; q++) a3[a][q] += sc[u3 * 17 + a * 4 + q];
        float4 res;
        #pragma unroll
        for (int a = 0; a < 4; a++) {
            float v = fmaxf(fmaxf(a3[a][0], a3[a][1]), fmaxf(a3[a][2], a3[a][3]));
            rres[a] = fmaxf(v + b3s[oc30 + a], 0.f);
        }
        res.x = rres[0]; res.y = rres[1]; res.z = rres[2]; res.w = rres[3];
        *(float4*)&out3[img * 288 + pos * 32 + oc30] = res;
    }

    // --- fused BN partial sums: single-writer LDS grid then 64 atomics ---
    __syncthreads();                     // sc reads done -> B reusable
    for (int i = tid; i < 576; i += 256) B[i] = 0.f;
    __syncthreads();
    if (writer) {
        #pragma unroll
        for (int a = 0; a < 4; a++) {
            B[pos * 64 + oc30 + a]      = rres[a];
            B[pos * 64 + 32 + oc30 + a] = rres[a] * rres[a];
        }
    }
    __syncthreads();
    if (tid < 64) {
        int c = tid & 31, part = tid >> 5;   // part 0 = S, 1 = SS
        float s = 0.f;
        #pragma unroll
        for (int p = 0; p < 9; p++) s += B[p * 64 + part * 32 + c];
        atomicAdd(&gstats[part * 32 + c], s);
    }
}

// ---------------------------------------------------------------------------
// Kernel 3: BN-finalize + BN-apply + MLP + argmax + 3 selection layers.
// 512-thread blocks, K-split-2 everywhere (r1 structure).
// NEW this round: selection layers 1/2 stage K-tiles of ALL THREE expert
// matrices into LDS (west[3][16][128], 24 KB) with register prefetch of the
// next tile (conv-kernel pattern). Each weight word is now loaded ONCE per
// block (sel1 1.18MB->442KB, sel2 524KB->196KB), loads are bulk/coalesced
// and off the critical path; the consume side becomes conflict-free LDS
// reads. FLOPs unchanged (compute still only the selected expert). sel1
// tile-0 prefetch issues before the logits phase to hide first-tile latency.
// ---------------------------------------------------------------------------
__global__ __launch_bounds__(512) void mlp_select_kernel(
    const float* __restrict__ out3, const float* __restrict__ gstats,
    const float* __restrict__ bng, const float* __restrict__ bnb,
    const float* __restrict__ pw1, const float* __restrict__ pb1,
    const float* __restrict__ pw2, const float* __restrict__ pb2,
    const float* __restrict__ pw3, const float* __restrict__ pb3,
    const float* __restrict__ ew1, const float* __restrict__ eb1,
    const float* __restrict__ ew2, const float* __restrict__ eb2,
    const float* __restrict__ ew3, const float* __restrict__ eb3,
    float* __restrict__ out)
{
    const int tid = threadIdx.x;          // 0..511
    const int img0 = blockIdx.x * 8;

    __shared__ float ysT[288 * 14];       // [j][e], stride 14
    __shared__ float hAT[128 * 14];
    __shared__ float hBT[128 * 14];
    __shared__ float wst[32 * 128];       // MLP weight tile / K-reduce scratch
    __shared__ float west[3 * 16 * 128];  // 3-expert K-tile (24 KB)
    __shared__ float lgp[48];
    __shared__ float sp[160];
    __shared__ int   acts[8];
    __shared__ float sa[32], sb[32];

    // BN finalize from global atomic sums (redundant per block; ~free)
    if (tid < 32) {
        float S = gstats[tid], SS = gstats[32 + tid];
        const float inv_n = 1.f / (4096.f * 9.f);
        float mean = S * inv_n;
        float var = SS * inv_n - mean * mean;
        float a = bng[tid] * rsqrtf(var + 1e-5f);
        sa[tid] = a;
        sb[tid] = bnb[tid] - a * mean;
    }
    __syncthreads();

    // stage + BN: 8*72 = 576 float4 reads, scatter-transpose into ysT
    for (int it = 0; it < 2; it++) {
        int i4 = it * 512 + tid;
        if (i4 < 576) {
            int e = i4 / 72, jq = i4 - e * 72;
            float4 v = *(const float4*)&out3[(img0 + e) * 288 + jq * 4];
            int j = jq * 4;
            ysT[(j + 0) * 14 + e] = fmaf(sa[(j + 0) & 31], v.x, sb[(j + 0) & 31]);
            ysT[(j + 1) * 14 + e] = fmaf(sa[(j + 1) & 31], v.y, sb[(j + 1) & 31]);
            ysT[(j + 2) * 14 + e] = fmaf(sa[(j + 2) & 31], v.z, sb[(j + 2) & 31]);
            ysT[(j + 3) * 14 + e] = fmaf(sa[(j + 3) & 31], v.w, sb[(j + 3) & 31]);
        }
    }

    const int kg = tid >> 8;              // K-half 0/1 (4 waves each)
    const int t8 = tid & 255;
    const int n4 = t8 & 31;               // neuron quad: n = n4*4 .. n4*4+3
    const int eE = t8 >> 5;               // example 0..7 (half-wave uniform)
    const int j0 = kg * 16;               // per-tile j-half for MLP staged layers
    const int srow16 = tid >> 5;          // expert-staging row 0..15
    const int sc4b   = tid & 31;          // expert-staging float4 column
    float acc[4];

    // layer 1: 288 -> 128, relu — K tiled by 32 (staged in wst), K-split-2
    {
        acc[0] = 0.f; acc[1] = 0.f; acc[2] = 0.f; acc[3] = 0.f;
        for (int t = 0; t < 9; t++) {
            __syncthreads();              // first iter also covers ysT staging
            #pragma unroll
            for (int s = 0; s < 2; s++) {
                int idx = s * 512 + tid;  // 1024 float4 slots
                int row = idx >> 5, c4 = idx & 31;
                int k = t * 32 + row;
                int i = (k & 31) * 9 + (k >> 5);
                *(float4*)&wst[row * 128 + c4 * 4] =
                    *(const float4*)&pw1[i * 128 + c4 * 4];
            }
            __syncthreads();
            #pragma unroll
            for (int j = 0; j < 16; j++) {
                float4 w = *(const float4*)&wst[(j0 + j) * 128 + n4 * 4];
                float yv = ysT[(t * 32 + j0 + j) * 14 + eE];
                acc[0] = fmaf(yv, w.x, acc[0]); acc[1] = fmaf(yv, w.y, acc[1]);
                acc[2] = fmaf(yv, w.z, acc[2]); acc[3] = fmaf(yv, w.w, acc[3]);
            }
        }
        __syncthreads();                  // last tile reads done -> wst reusable
        if (kg) *(float4*)&wst[t8 * 4] = make_float4(acc[0], acc[1], acc[2], acc[3]);
        __syncthreads();
        if (!kg) {
            float4 p = *(const float4*)&wst[t8 * 4];
            float4 b = *(const float4*)&pb1[n4 * 4];
            hAT[(n4 * 4 + 0) * 14 + eE] = fmaxf(acc[0] + p.x + b.x, 0.f);
            hAT[(n4 * 4 + 1) * 14 + eE] = fmaxf(acc[1] + p.y + b.y, 0.f);
            hAT[(n4 * 4 + 2) * 14 + eE] = fmaxf(acc[2] + p.z + b.z, 0.f);
            hAT[(n4 * 4 + 3) * 14 + eE] = fmaxf(acc[3] + p.w + b.w, 0.f);
        }
    }

    // layer 2: 128 -> 128, relu — staged tiles, K-split-2
    {
        acc[0] = 0.f; acc[1] = 0.f; acc[2] = 0.f; acc[3] = 0.f;
        for (int t = 0; t < 4; t++) {
            __syncthreads();              // hAT writes + prior wst reads done
            #pragma unroll
            for (int s = 0; s < 2; s++) {
                int idx = s * 512 + tid;
                int row = idx >> 5, c4 = idx & 31;
                int k = t * 32 + row;
                *(float4*)&wst[row * 128 + c4 * 4] =
                    *(const float4*)&pw2[k * 128 + c4 * 4];
            }
            __syncthreads();
            #pragma unroll
            for (int j = 0; j < 16; j++) {
                float4 w = *(const float4*)&wst[(j0 + j) * 128 + n4 * 4];
                float hv = hAT[(t * 32 + j0 + j) * 14 + eE];
                acc[0] = fmaf(hv, w.x, acc[0]); acc[1] = fmaf(hv, w.y, acc[1]);
                acc[2] = fmaf(hv, w.z, acc[2]); acc[3] = fmaf(hv, w.w, acc[3]);
            }
        }
        __syncthreads();
        if (kg) *(float4*)&wst[t8 * 4] = make_float4(acc[0], acc[1], acc[2], acc[3]);
        __syncthreads();
        if (!kg) {
            float4 p = *(const float4*)&wst[t8 * 4];
            float4 b = *(const float4*)&pb2[n4 * 4];
            hBT[(n4 * 4 + 0) * 14 + eE] = fmaxf(acc[0] + p.x + b.x, 0.f);
            hBT[(n4 * 4 + 1) * 14 + eE] = fmaxf(acc[1] + p.y + b.y, 0.f);
            hBT[(n4 * 4 + 2) * 14 + eE] = fmaxf(acc[2] + p.z + b.z, 0.f);
            hBT[(n4 * 4 + 3) * 14 + eE] = fmaxf(acc[3] + p.w + b.w, 0.f);
        }
    }
    __syncthreads();

    // prefetch sel1 tile 0 (all 3 experts) — in flight across the logits phase
    float4 pfe[3];
    {
        const int i0 = (srow16 & 31) * 9 + (srow16 >> 5);   // k = srow16, tile 0
        #pragma unroll
        for (int s = 0; s < 3; s++)
            pfe[s] = *(const float4*)&ew1[s * 36864 + i0 * 128 + sc4b * 4];
    }

    // logits 128 -> 3: 24 (e,o) pairs x 2 K-partials of 64 (UNCHANGED order)
    if (tid < 48) {
        int pr = tid & 1, eo = tid >> 1;
        int e = eo / 3, o = eo - e * 3;
        float s = pr ? 0.f : pb3[o];
        const int k0 = pr * 64;
        for (int k = k0; k < k0 + 64; k++) s = fmaf(hBT[k * 14 + e], pw3[k * 3 + o], s);
        lgp[tid] = s;
    }
    __syncthreads();
    if (tid < 8) {
        float l0 = lgp[(tid * 3 + 0) * 2] + lgp[(tid * 3 + 0) * 2 + 1];
        float l1 = lgp[(tid * 3 + 1) * 2] + lgp[(tid * 3 + 1) * 2 + 1];
        float l2 = lgp[(tid * 3 + 2) * 2] + lgp[(tid * 3 + 2) * 2 + 1];
        int a = 0; float best = l0;
        if (l1 > best) { best = l1; a = 1; }
        if (l2 > best) { best = l2; a = 2; }
        acts[tid] = a;
        out[4096 * 10 + img0 + tid] = (float)a;
    }
    __syncthreads();

    const int a = acts[eE];               // half-wave-uniform expert id

    // selection layer 1: 288 -> 128, 3-expert staged K-tiles of 16, K-split-2
    {
        acc[0] = 0.f; acc[1] = 0.f; acc[2] = 0.f; acc[3] = 0.f;
        for (int t = 0; t < 18; t++) {
            __syncthreads();              // prior west reads done
            #pragma unroll
            for (int s = 0; s < 3; s++)
                *(float4*)&west[s * 2048 + srow16 * 128 + sc4b * 4] = pfe[s];
            if (t < 17) {
                int k = (t + 1) * 16 + srow16;
                int i = (k & 31) * 9 + (k >> 5);
                #pragma unroll
                for (int s = 0; s < 3; s++)
                    pfe[s] = *(const float4*)&ew1[s * 36864 + i * 128 + sc4b * 4];
            }
            __syncthreads();
            #pragma unroll
            for (int j = 0; j < 8; j++) {
                int kr = kg * 8 + j;
                float4 w = *(const float4*)&west[a * 2048 + kr * 128 + n4 * 4];
                float yv = ysT[(t * 16 + kr) * 14 + eE];
                acc[0] = fmaf(yv, w.x, acc[0]); acc[1] = fmaf(yv, w.y, acc[1]);
                acc[2] = fmaf(yv, w.z, acc[2]); acc[3] = fmaf(yv, w.w, acc[3]);
            }
        }
        // prefetch sel2 tile 0 while reducing
        #pragma unroll
        for (int s = 0; s < 3; s++)
            pfe[s] = *(const float4*)&ew2[s * 16384 + srow16 * 128 + sc4b * 4];
        __syncthreads();                  // west reads done; wst free
        if (kg) *(float4*)&wst[t8 * 4] = make_float4(acc[0], acc[1], acc[2], acc[3]);
        __syncthreads();
        if (!kg) {
            float4 p = *(const float4*)&wst[t8 * 4];
            float4 b = *(const float4*)&eb1[a * 128 + n4 * 4];
            hAT[(n4 * 4 + 0) * 14 + eE] = acc[0] + p.x + b.x;
            hAT[(n4 * 4 + 1) * 14 + eE] = acc[1] + p.y + b.y;
            hAT[(n4 * 4 + 2) * 14 + eE] = acc[2] + p.z + b.z;
            hAT[(n4 * 4 + 3) * 14 + eE] = acc[3] + p.w + b.w;
        }
    }

    // selection layer 2: 128 -> 128, 3-expert staged K-tiles of 16, K-split-2
    {
        acc[0] = 0.f; acc[1] = 0.f; acc[2] = 0.f; acc[3] = 0.f;
        for (int t = 0; t < 8; t++) {
            __syncthreads();              // hAT writes + prior west reads done
            #pragma unroll
            for (int s = 0; s < 3; s++)
                *(float4*)&west[s * 2048 + srow16 * 128 + sc4b * 4] = pfe[s];
            if (t < 7) {
                int k = (t + 1) * 16 + srow16;
                #pragma unroll
                for (int s = 0; s < 3; s++)
                    pfe[s] = *(const float4*)&ew2[s * 16384 + k * 128 + sc4b * 4];
            }
            __syncthreads();
            #pragma unroll
            for (int j = 0; j < 8; j++) {
                int kr = kg * 8 + j;
                float4 w = *(const float4*)&west[a * 2048 + kr * 128 + n4 * 4];
                float hv = hAT[(t * 16 + kr) * 14 + eE];
                acc[0] = fmaf(hv, w.x, acc[0]); acc[1] = fmaf(hv, w.y, acc[1]);
                acc[2] = fmaf(hv, w.z, acc[2]); acc[3] = fmaf(hv, w.w, acc[3]);
            }
        }
        __syncthreads();
        if (kg) *(float4*)&wst[t8 * 4] = make_float4(acc[0], acc[1], acc[2], acc[3]);
        __syncthreads();
        if (!kg) {
            float4 p = *(const float4*)&wst[t8 * 4];
            float4 b = *(const float4*)&eb2[a * 128 + n4 * 4];
            hBT[(n4 * 4 + 0) * 14 + eE] = acc[0] + p.x + b.x;
            hBT[(n4 * 4 + 1) * 14 + eE] = acc[1] + p.y + b.y;
            hBT[(n4 * 4 + 2) * 14 + eE] = acc[2] + p.z + b.z;
            hBT[(n4 * 4 + 3) * 14 + eE] = acc[3] + p.w + b.w;
        }
    }
    __syncthreads();

    // selection layer 3: 128 -> 10: 80 (e,o) pairs x 2 K-partials of 64
    if (tid < 160) {
        int pr = (tid >= 80) ? 1 : 0;
        int idx = tid - pr * 80;
        int e = idx / 10, o = idx - e * 10;
        int aa = acts[e];
        const float* w3 = &ew3[aa * 1280];
        float s = pr ? 0.f : eb3[aa * 10 + o];
        const int k0 = pr * 64;
        for (int k = k0; k < k0 + 64; k++) s = fmaf(hBT[k * 14 + e], w3[k * 10 + o], s);
        sp[tid] = s;
    }
    __syncthreads();
    if (tid < 80) {
        int e = tid / 10, o = tid - e * 10;
        out[(img0 + e) * 10 + o] = sp[tid] + sp[tid + 80];
    }
}

// ---------------------------------------------------------------------------
extern "C" void kernel_launch(void* const* d_in, const int* in_sizes, int n_in,
                              void* d_out, int out_size, void* d_ws, size_t ws_size,
                              hipStream_t stream)
{
    const float* x   = (const float*)d_in[0];
    const float* cw1 = (const float*)d_in[1];
    const float* cb1 = (const float*)d_in[2];
    const float* cw2 = (const float*)d_in[3];
    const float* cb2 = (const float*)d_in[4];
    const float* cw3 = (const float*)d_in[5];
    const float* cb3 = (const float*)d_in[6];
    const float* bng = (const float*)d_in[7];
    const float* bnb = (const float*)d_in[8];
    const float* pw1 = (const float*)d_in[9];
    const float* pb1 = (const float*)d_in[10];
    const float* pw2 = (const float*)d_in[11];
    const float* pb2 = (const float*)d_in[12];
    const float* pw3 = (const float*)d_in[13];
    const float* pb3 = (const float*)d_in[14];
    const float* ew1 = (const float*)d_in[15];
    const float* eb1 = (const float*)d_in[16];
    const float* ew2 = (const float*)d_in[17];
    const float* eb2 = (const float*)d_in[18];
    const float* ew3 = (const float*)d_in[19];
    const float* eb3 = (const float*)d_in[20];

    float* out     = (float*)d_out;
    float* out3    = (float*)d_ws;                    // 4096*288
    float* gstats  = out3 + 4096 * 288;               // 64 (atomic S/SS)
    float* packed2 = gstats + 64;                     // 9216
    float* packed3 = packed2 + 9216;                  // 9216

    hipMemsetAsync(gstats, 0, 64 * sizeof(float), stream);
    repack_kernel<<<72, 256, 0, stream>>>(cw2, cw3, packed2, packed3);
    fused_conv_kernel<<<4096, 256, 0, stream>>>(x, cw1, cb1, packed2, cb2,
                                                packed3, cb3, out3, gstats);
    mlp_select_kernel<<<512, 512, 0, stream>>>(out3, gstats, bng, bnb,
                                               pw1, pb1, pw2, pb2, pw3, pb3,
                                               ew1, eb1, ew2, eb2, ew3, eb3, out);
}

// Round 3
// 467.061 us; speedup vs baseline: 1.0240x; 1.0240x over previous
//
#include <hip/hip_runtime.h>

// ---------------------------------------------------------------------------
// Kernel 0: repack conv2/conv3 weights into [ic*9+tap][oc] linear layout.
// UNCHANGED.
// ---------------------------------------------------------------------------
__global__ __launch_bounds__(256) void repack_kernel(
    const float* __restrict__ cw2, const float* __restrict__ cw3,
    float* __restrict__ packed2, float* __restrict__ packed3)
{
    int t = blockIdx.x * 256 + threadIdx.x;   // grid 72*256 = 18432 = 2*9216
    if (t < 9216) {
        int oc = t & 31, r = t >> 5;          // r = ic*9+tap in [0,288)
        packed2[t] = cw2[oc * 288 + r];
    } else {
        int t2 = t - 9216;
        int oc = t2 & 31, r = t2 >> 5;
        packed3[t2] = cw3[oc * 288 + r];
    }
}

// ---------------------------------------------------------------------------
// Kernel 1: fused conv stack + fused BatchNorm partial-sum epilogue.
// NEW this round (conv3 only): K-split moved to LANE PAIRS (g3 = tid&1,
// u3 = tid>>1). Active set becomes tid<144 -> waves 0,1 fully active,
// wave 2 partial, wave 3 exec=0 (execz-skips the whole conv3 stream; was
// issuing 2304 FMAs for 8 live lanes). K-reduction becomes an in-wave
// __shfl_xor(.,1) -> conv3 LDS scratch + 2 barriers removed. Sum order
// identical (even lane adds odd partial) -> bit-exact vs r1.
// conv1/conv2/pool UNCHANGED.
// ---------------------------------------------------------------------------
__global__ __launch_bounds__(256)
void fused_conv_kernel(
    const float* __restrict__ x,
    const float* __restrict__ cw1, const float* __restrict__ cb1,
    const float* __restrict__ packed2, const float* __restrict__ cb2,
    const float* __restrict__ packed3, const float* __restrict__ cb3,
    float* __restrict__ out3, float* __restrict__ gstats)
{
    const int img = blockIdx.x;
    const int tid = threadIdx.x;

    __shared__ float A[1220];         // xs1(900)+w1s(288)+b1s(32) | wck2(1152)
    __shared__ float B[8320];         // xs2 (32 x 260) | scratch/xs3/wck3
    __shared__ float b2s[32], b3s[32];

    float* xs1  = A;                  // 900: 30x30 padded image
    float* w1s  = A + 900;            // 288
    float* b1s  = A + 1188;           // 32
    float* wck2 = A;                  // 1152: conv2 4-ic chunk (after conv1)
    float* xs2  = B;                  // 32 planes x 260
    float* sc   = B;                  // reduction scratch head (conv2 only now)
    float* xs3  = B + 1280;           // 2880: 32 x 90 -> [1280,4160)
    float* wck3 = B + 4160;           // 2304: conv3 8-ic chunk -> [4160,6464)
    float* sc2  = B + 5073;           // pool scratch -> [5102,8320)

    // --- zero xs1 pads + all of B ---
    for (int i = tid; i < 900;  i += 256) xs1[i] = 0.f;
    for (int i = tid; i < 8320; i += 256) B[i] = 0.f;
    __syncthreads();

    // --- stage input image + conv1 weights + biases ---
    for (int i = tid; i < 784; i += 256) {
        int yy = i / 28, xx = i % 28;
        xs1[(yy + 1) * 30 + xx + 1] = x[img * 784 + i];
    }
    for (int i = tid; i < 288; i += 256) {
        int oc = i & 31, tap = i >> 5;
        w1s[i] = cw1[oc * 9 + tap];
    }
    if (tid < 32) { b1s[tid] = cb1[tid]; b2s[tid] = cb2[tid]; b3s[tid] = cb3[tid]; }
    __syncthreads();

    // --- conv1 (1->32) + relu + pool -> xs2 (swizzled) ---
    {
        const int c1 = tid & 31;
        float w1r[9];
        #pragma unroll
        for (int t = 0; t < 9; t++) w1r[t] = w1s[t * 32 + c1];
        const float bias1 = b1s[c1];
        for (int o = tid; o < 32 * 196; o += 256) {
            int p = o >> 5;
            int py = p / 14, px = p % 14;
            int base = (2 * py) * 30 + 2 * px;
            float P[16];
            #pragma unroll
            for (int r = 0; r < 4; r++) {
                float2 u0 = *(const float2*)&xs1[base + r * 30];
                float2 u1 = *(const float2*)&xs1[base + r * 30 + 2];
                P[r * 4 + 0] = u0.x; P[r * 4 + 1] = u0.y;
                P[r * 4 + 2] = u1.x; P[r * 4 + 3] = u1.y;
            }
            float a00 = 0.f, a01 = 0.f, a10 = 0.f, a11 = 0.f;
            #pragma unroll
            for (int ky = 0; ky < 3; ky++)
                #pragma unroll
                for (int kx = 0; kx < 3; kx++) {
                    float w = w1r[ky * 3 + kx];
                    a00 = fmaf(P[ky * 4 + kx],           w, a00);
                    a01 = fmaf(P[ky * 4 + kx + 1],       w, a01);
                    a10 = fmaf(P[(ky + 1) * 4 + kx],     w, a10);
                    a11 = fmaf(P[(ky + 1) * 4 + kx + 1], w, a11);
                }
            float v = fmaxf(fmaxf(fmaxf(a00, a01), fmaxf(a10, a11)) + bias1, 0.f);
            int r = py + 1, col = px + 1;
            xs2[c1 * 260 + r * 16 + ((((col >> 2) + r) & 3) << 2) + (col & 3)] = v;
        }
    }

    // --- conv2: 4oc x 14 cols, K-split-2 over 8 chunks of 4 ic ---
    const int g  = tid >> 7;            // K-group 0..1 (2 waves each)
    const int u  = tid & 127;           // unit; active if u < 112
    const int cb = u & 7, R = u >> 3;   // oc-quad, prepool row 0..13
    const int oc0 = cb * 4;
    const bool act2 = (u < 112);

    float acc[4][14];
    #pragma unroll
    for (int a = 0; a < 4; a++)
        #pragma unroll
        for (int c = 0; c < 14; c++) acc[a][c] = 0.f;

    float pf[5];                        // 1152 = 4.5*256
    #pragma unroll
    for (int k = 0; k < 5; k++) {
        int idx = tid + k * 256;
        pf[k] = (idx < 1152) ? packed2[idx] : 0.f;
    }

    for (int ch = 0; ch < 8; ch++) {
        __syncthreads();                // conv1/xs2 writes + prior wck2 reads done
        #pragma unroll
        for (int k = 0; k < 5; k++) {
            int idx = tid + k * 256;
            if (idx < 1152) wck2[idx] = pf[k];
        }
        if (ch < 7) {
            #pragma unroll
            for (int k = 0; k < 5; k++) {
                int idx = tid + k * 256;
                pf[k] = (idx < 1152) ? packed2[(ch + 1) * 1152 + idx] : 0.f;
            }
        }
        __syncthreads();
        if (act2) {
            #pragma unroll
            for (int d = 0; d < 2; d++) {
                const int ld = g * 2 + d;            // local ic 0..3
                const int ic = ch * 4 + ld;
                const float* wd = &wck2[ld * 288 + oc0];
                const int pb = ic * 260;
                #pragma unroll
                for (int ky = 0; ky < 3; ky++) {
                    const int rp = R + ky;
                    const int rb = pb + rp * 16;
                    float row[16];
                    #pragma unroll
                    for (int q = 0; q < 4; q++) {
                        const float4 t = *(const float4*)&xs2[rb + (((q + rp) & 3) << 2)];
                        row[q * 4 + 0] = t.x; row[q * 4 + 1] = t.y;
                        row[q * 4 + 2] = t.z; row[q * 4 + 3] = t.w;
                    }
                    const float4 wa = *(const float4*)&wd[(ky * 3 + 0) * 32];
                    const float4 wb = *(const float4*)&wd[(ky * 3 + 1) * 32];
                    const float4 wc = *(const float4*)&wd[(ky * 3 + 2) * 32];
                    #pragma unroll
                    for (int c = 0; c < 14; c++) {
                        acc[0][c] = fmaf(row[c],     wa.x, acc[0][c]);
                        acc[1][c] = fmaf(row[c],     wa.y, acc[1][c]);
                        acc[2][c] = fmaf(row[c],     wa.z, acc[2][c]);
                        acc[3][c] = fmaf(row[c],     wa.w, acc[3][c]);
                        acc[0][c] = fmaf(row[c + 1], wb.x, acc[0][c]);
                        acc[1][c] = fmaf(row[c + 1], wb.y, acc[1][c]);
                        acc[2][c] = fmaf(row[c + 1], wb.z, acc[2][c]);
                        acc[3][c] = fmaf(row[c + 1], wb.w, acc[3][c]);
                        acc[0][c] = fmaf(row[c + 2], wc.x, acc[0][c]);
                        acc[1][c] = fmaf(row[c + 2], wc.y, acc[1][c]);
                        acc[2][c] = fmaf(row[c + 2], wc.z, acc[2][c]);
                        acc[3][c] = fmaf(row[c + 2], wc.w, acc[3][c]);
                    }
                }
            }
        }
    }

    // --- conv2 K-reduction (1 round, stride-57 scratch in B head, max 6382) ---
    __syncthreads();                     // all xs2 patch reads done
    if (g == 1 && act2) {
        #pragma unroll
        for (int a = 0; a < 4; a++)
            #pragma unroll
            for (int c = 0; c < 14; c++) sc[u * 57 + a * 14 + c] = acc[a][c];
    }
    __syncthreads();
    if (g == 0 && act2) {
        #pragma unroll
        for (int a = 0; a < 4; a++)
            #pragma unroll
            for (int c = 0; c < 14; c++) acc[a][c] += sc[u * 57 + a * 14 + c];
    }
    __syncthreads();                     // reduction scratch retires

    // --- zero xs3 + pool 14x14->7x7 (register hmax, odd/even R via sc2) ---
    for (int i = tid; i < 2880; i += 256) xs3[i] = 0.f;
    float hm[4][7];
    if (g == 0 && act2) {
        #pragma unroll
        for (int a = 0; a < 4; a++)
            #pragma unroll
            for (int c = 0; c < 7; c++)
                hm[a][c] = fmaxf(acc[a][2 * c], acc[a][2 * c + 1]);
        if (R & 1) {                     // sc2 idx max 111*29+27=3246 -> abs 8319
            #pragma unroll
            for (int a = 0; a < 4; a++)
                #pragma unroll
                for (int c = 0; c < 7; c++) sc2[u * 29 + a * 7 + c] = hm[a][c];
        }
    }
    __syncthreads();
    if (g == 0 && act2 && !(R & 1)) {
        const int py = R >> 1;           // 0..6
        #pragma unroll
        for (int a = 0; a < 4; a++)
            #pragma unroll
            for (int c = 0; c < 7; c++) {
                float v = fmaxf(hm[a][c], sc2[(u + 8) * 29 + a * 7 + c]);
                v = fmaxf(v + b2s[oc0 + a], 0.f);
                xs3[(oc0 + a) * 90 + (py + 1) * 10 + (c + 1)] = v;
            }
    }

    // --- conv3 (32->32, 7x7) + relu + pool(7->3 floor) ---
    // K-split on LANE PAIRS: g3 = tid&1 picks the 4-ic half; active tid<144.
    // Wave 3 has exec=0 for the whole compute stream (execz skip).
    const int g3 = tid & 1;
    const int u3 = tid >> 1;             // 0..127
    const bool act3 = (u3 < 72);         // tid < 144
    const int cq3 = u3 & 7, pos = u3 >> 3;   // oc-quad, pooled pos 0..8
    const int oc30 = cq3 * 4;
    const int py3 = pos / 3, px3 = pos % 3;
    const int base3 = (2 * py3) * 10 + 2 * px3;

    float a3[4][4];
    #pragma unroll
    for (int a = 0; a < 4; a++)
        #pragma unroll
        for (int q = 0; q < 4; q++) a3[a][q] = 0.f;

    float pg[9];                        // 2304 = 9*256
    #pragma unroll
    for (int k = 0; k < 9; k++) pg[k] = packed3[tid + k * 256];

    for (int ch = 0; ch < 4; ch++) {
        __syncthreads();                 // pool/xs3 writes + prior wck3 reads done
        #pragma unroll
        for (int k = 0; k < 9; k++) wck3[tid + k * 256] = pg[k];
        if (ch < 3) {
            #pragma unroll
            for (int k = 0; k < 9; k++) pg[k] = packed3[(ch + 1) * 2304 + tid + k * 256];
        }
        __syncthreads();
        if (act3) {
            #pragma unroll 2
            for (int d = 0; d < 4; d++) {
                const int ld = g3 * 4 + d;
                const int ic = ch * 8 + ld;
                const float* xp = &xs3[ic * 90 + base3];
                float P[16];
                #pragma unroll
                for (int r = 0; r < 4; r++) {
                    float2 u0 = *(const float2*)&xp[r * 10];
                    float2 u1 = *(const float2*)&xp[r * 10 + 2];
                    P[r * 4 + 0] = u0.x; P[r * 4 + 1] = u0.y;
                    P[r * 4 + 2] = u1.x; P[r * 4 + 3] = u1.y;
                }
                const float* wd = &wck3[ld * 288 + oc30];
                #pragma unroll
                for (int tap = 0; tap < 9; tap++) {
                    const int ky = tap / 3, kx = tap % 3;
                    const float4 wv = *(const float4*)&wd[tap * 32];
                    const float x00 = P[ky * 4 + kx];
                    const float x01 = P[ky * 4 + kx + 1];
                    const float x10 = P[(ky + 1) * 4 + kx];
                    const float x11 = P[(ky + 1) * 4 + kx + 1];
                    a3[0][0] = fmaf(x00, wv.x, a3[0][0]); a3[0][1] = fmaf(x01, wv.x, a3[0][1]);
                    a3[0][2] = fmaf(x10, wv.x, a3[0][2]); a3[0][3] = fmaf(x11, wv.x, a3[0][3]);
                    a3[1][0] = fmaf(x00, wv.y, a3[1][0]); a3[1][1] = fmaf(x01, wv.y, a3[1][1]);
                    a3[1][2] = fmaf(x10, wv.y, a3[1][2]); a3[1][3] = fmaf(x11, wv.y, a3[1][3]);
                    a3[2][0] = fmaf(x00, wv.z, a3[2][0]); a3[2][1] = fmaf(x01, wv.z, a3[2][1]);
                    a3[2][2] = fmaf(x10, wv.z, a3[2][2]); a3[2][3] = fmaf(x11, wv.z, a3[2][3]);
                    a3[3][0] = fmaf(x00, wv.w, a3[3][0]); a3[3][1] = fmaf(x01, wv.w, a3[3][1]);
                    a3[3][2] = fmaf(x10, wv.w, a3[3][2]); a3[3][3] = fmaf(x11, wv.w, a3[3][3]);
                }
            }
        }
    }

    // --- conv3 K-reduction: in-wave lane-pair shuffle (even lane = old g0) ---
    float rres[4];
    const bool writer = (g3 == 0 && act3);
    if (act3) {
        #pragma unroll
        for (int a = 0; a < 4; a++)
            #pragma unroll
            for (int q = 0; q < 4; q++)
                a3[a][q] += __shfl_xor(a3[a][q], 1);
    }
    if (writer) {
        float4 res;
        #pragma unroll
        for (int a = 0; a < 4; a++) {
            float v = fmaxf(fmaxf(a3[a][0], a3[a][1]), fmaxf(a3[a][2], a3[a][3]));
            rres[a] = fmaxf(v + b3s[oc30 + a], 0.f);
        }
        res.x = rres[0]; res.y = rres[1]; res.z = rres[2]; res.w = rres[3];
        *(float4*)&out3[img * 288 + pos * 32 + oc30] = res;
    }

    // --- fused BN partial sums: single-writer LDS grid then 64 atomics ---
    // B[0..576) does not overlap xs3/wck3, so no barrier needed before zero.
    for (int i = tid; i < 576; i += 256) B[i] = 0.f;
    __syncthreads();
    if (writer) {
        #pragma unroll
        for (int a = 0; a < 4; a++) {
            B[pos * 64 + oc30 + a]      = rres[a];
            B[pos * 64 + 32 + oc30 + a] = rres[a] * rres[a];
        }
    }
    __syncthreads();
    if (tid < 64) {
        int c = tid & 31, part = tid >> 5;   // part 0 = S, 1 = SS
        float s = 0.f;
        #pragma unroll
        for (int p = 0; p < 9; p++) s += B[p * 64 + part * 32 + c];
        atomicAdd(&gstats[part * 32 + c], s);
    }
}

// ---------------------------------------------------------------------------
// Kernel 3: BN-finalize + BN-apply + MLP + argmax + 3 selection layers.
// REVERTED to the r1 version (measured best: 413 us total / ~100 us tail).
// 512-thread blocks, K-split-2 on every layer; MLP weights staged through
// LDS; selection layers keep direct per-half-wave expert streams (the r2
// 3-expert LDS staging regressed: 36 tiny-tile barriers at 2 blocks/CU).
// ---------------------------------------------------------------------------
__global__ __launch_bounds__(512) void mlp_select_kernel(
    const float* __restrict__ out3, const float* __restrict__ gstats,
    const float* __restrict__ bng, const float* __restrict__ bnb,
    const float* __restrict__ pw1, const float* __restrict__ pb1,
    const float* __restrict__ pw2, const float* __restrict__ pb2,
    const float* __restrict__ pw3, const float* __restrict__ pb3,
    const float* __restrict__ ew1, const float* __restrict__ eb1,
    const float* __restrict__ ew2, const float* __restrict__ eb2,
    const float* __restrict__ ew3, const float* __restrict__ eb3,
    float* __restrict__ out)
{
    const int tid = threadIdx.x;          // 0..511
    const int img0 = blockIdx.x * 8;

    __shared__ float ysT[288 * 14];       // [j][e], stride 14
    __shared__ float hAT[128 * 14];
    __shared__ float hBT[128 * 14];
    __shared__ float wst[32 * 128];       // staged weight tile / K-reduce scratch
    __shared__ float lgp[48];
    __shared__ float sp[160];
    __shared__ int   acts[8];
    __shared__ float sa[32], sb[32];

    // BN finalize from global atomic sums (redundant per block; ~free)
    if (tid < 32) {
        float S = gstats[tid], SS = gstats[32 + tid];
        const float inv_n = 1.f / (4096.f * 9.f);
        float mean = S * inv_n;
        float var = SS * inv_n - mean * mean;
        float a = bng[tid] * rsqrtf(var + 1e-5f);
        sa[tid] = a;
        sb[tid] = bnb[tid] - a * mean;
    }
    __syncthreads();

    // stage + BN: 8*72 = 576 float4 reads, scatter-transpose into ysT
    for (int it = 0; it < 2; it++) {
        int i4 = it * 512 + tid;
        if (i4 < 576) {
            int e = i4 / 72, jq = i4 - e * 72;
            float4 v = *(const float4*)&out3[(img0 + e) * 288 + jq * 4];
            int j = jq * 4;
            ysT[(j + 0) * 14 + e] = fmaf(sa[(j + 0) & 31], v.x, sb[(j + 0) & 31]);
            ysT[(j + 1) * 14 + e] = fmaf(sa[(j + 1) & 31], v.y, sb[(j + 1) & 31]);
            ysT[(j + 2) * 14 + e] = fmaf(sa[(j + 2) & 31], v.z, sb[(j + 2) & 31]);
            ysT[(j + 3) * 14 + e] = fmaf(sa[(j + 3) & 31], v.w, sb[(j + 3) & 31]);
        }
    }

    const int kg = tid >> 8;              // K-half 0/1 (4 waves each)
    const int t8 = tid & 255;
    const int n4 = t8 & 31;               // neuron quad: n = n4*4 .. n4*4+3
    const int eE = t8 >> 5;               // example 0..7 (half-wave uniform)
    const int j0 = kg * 16;               // per-tile j-half for staged layers
    float acc[4];

    // layer 1: 288 -> 128, relu — K tiled by 32 (staged in wst), K-split-2
    {
        acc[0] = 0.f; acc[1] = 0.f; acc[2] = 0.f; acc[3] = 0.f;
        for (int t = 0; t < 9; t++) {
            __syncthreads();              // first iter also covers ysT staging
            #pragma unroll
            for (int s = 0; s < 2; s++) {
                int idx = s * 512 + tid;  // 1024 float4 slots
                int row = idx >> 5, c4 = idx & 31;
                int k = t * 32 + row;
                int i = (k & 31) * 9 + (k >> 5);
                *(float4*)&wst[row * 128 + c4 * 4] =
                    *(const float4*)&pw1[i * 128 + c4 * 4];
            }
            __syncthreads();
            #pragma unroll
            for (int j = 0; j < 16; j++) {
                float4 w = *(const float4*)&wst[(j0 + j) * 128 + n4 * 4];
                float yv = ysT[(t * 32 + j0 + j) * 14 + eE];
                acc[0] = fmaf(yv, w.x, acc[0]); acc[1] = fmaf(yv, w.y, acc[1]);
                acc[2] = fmaf(yv, w.z, acc[2]); acc[3] = fmaf(yv, w.w, acc[3]);
            }
        }
        __syncthreads();                  // last tile reads done -> wst reusable
        if (kg) *(float4*)&wst[t8 * 4] = make_float4(acc[0], acc[1], acc[2], acc[3]);
        __syncthreads();
        if (!kg) {
            float4 p = *(const float4*)&wst[t8 * 4];
            float4 b = *(const float4*)&pb1[n4 * 4];
            hAT[(n4 * 4 + 0) * 14 + eE] = fmaxf(acc[0] + p.x + b.x, 0.f);
            hAT[(n4 * 4 + 1) * 14 + eE] = fmaxf(acc[1] + p.y + b.y, 0.f);
            hAT[(n4 * 4 + 2) * 14 + eE] = fmaxf(acc[2] + p.z + b.z, 0.f);
            hAT[(n4 * 4 + 3) * 14 + eE] = fmaxf(acc[3] + p.w + b.w, 0.f);
        }
    }

    // layer 2: 128 -> 128, relu — staged tiles, K-split-2
    {
        acc[0] = 0.f; acc[1] = 0.f; acc[2] = 0.f; acc[3] = 0.f;
        for (int t = 0; t < 4; t++) {
            __syncthreads();              // hAT writes + prior wst reads done
            #pragma unroll
            for (int s = 0; s < 2; s++) {
                int idx = s * 512 + tid;
                int row = idx >> 5, c4 = idx & 31;
                int k = t * 32 + row;
                *(float4*)&wst[row * 128 + c4 * 4] =
                    *(const float4*)&pw2[k * 128 + c4 * 4];
            }
            __syncthreads();
            #pragma unroll
            for (int j = 0; j < 16; j++) {
                float4 w = *(const float4*)&wst[(j0 + j) * 128 + n4 * 4];
                float hv = hAT[(t * 32 + j0 + j) * 14 + eE];
                acc[0] = fmaf(hv, w.x, acc[0]); acc[1] = fmaf(hv, w.y, acc[1]);
                acc[2] = fmaf(hv, w.z, acc[2]); acc[3] = fmaf(hv, w.w, acc[3]);
            }
        }
        __syncthreads();
        if (kg) *(float4*)&wst[t8 * 4] = make_float4(acc[0], acc[1], acc[2], acc[3]);
        __syncthreads();
        if (!kg) {
            float4 p = *(const float4*)&wst[t8 * 4];
            float4 b = *(const float4*)&pb2[n4 * 4];
            hBT[(n4 * 4 + 0) * 14 + eE] = fmaxf(acc[0] + p.x + b.x, 0.f);
            hBT[(n4 * 4 + 1) * 14 + eE] = fmaxf(acc[1] + p.y + b.y, 0.f);
            hBT[(n4 * 4 + 2) * 14 + eE] = fmaxf(acc[2] + p.z + b.z, 0.f);
            hBT[(n4 * 4 + 3) * 14 + eE] = fmaxf(acc[3] + p.w + b.w, 0.f);
        }
    }
    __syncthreads();

    // logits 128 -> 3: 24 (e,o) pairs x 2 K-partials of 64 (UNCHANGED order)
    if (tid < 48) {
        int pr = tid & 1, eo = tid >> 1;
        int e = eo / 3, o = eo - e * 3;
        float s = pr ? 0.f : pb3[o];
        const int k0 = pr * 64;
        for (int k = k0; k < k0 + 64; k++) s = fmaf(hBT[k * 14 + e], pw3[k * 3 + o], s);
        lgp[tid] = s;
    }
    __syncthreads();
    if (tid < 8) {
        float l0 = lgp[(tid * 3 + 0) * 2] + lgp[(tid * 3 + 0) * 2 + 1];
        float l1 = lgp[(tid * 3 + 1) * 2] + lgp[(tid * 3 + 1) * 2 + 1];
        float l2 = lgp[(tid * 3 + 2) * 2] + lgp[(tid * 3 + 2) * 2 + 1];
        int a = 0; float best = l0;
        if (l1 > best) { best = l1; a = 1; }
        if (l2 > best) { best = l2; a = 2; }
        acts[tid] = a;
        out[4096 * 10 + img0 + tid] = (float)a;
    }
    __syncthreads();

    const int a = acts[eE];               // half-wave-uniform expert id

    // selection layer 1: 288 -> 128, expert stream, K-split-2 (2x144)
    {
        const float* wb = ew1 + a * 36864;
        acc[0] = 0.f; acc[1] = 0.f; acc[2] = 0.f; acc[3] = 0.f;
        const int kb = kg * 144;
        for (int kk = 0; kk < 144; kk++) {
            int k = kb + kk;
            int i = (k & 31) * 9 + (k >> 5);
            float4 w = *(const float4*)&wb[i * 128 + n4 * 4];
            float yv = ysT[k * 14 + eE];
            acc[0] = fmaf(yv, w.x, acc[0]); acc[1] = fmaf(yv, w.y, acc[1]);
            acc[2] = fmaf(yv, w.z, acc[2]); acc[3] = fmaf(yv, w.w, acc[3]);
        }
        __syncthreads();                  // logits-phase hBT reads done; wst free
        if (kg) *(float4*)&wst[t8 * 4] = make_float4(acc[0], acc[1], acc[2], acc[3]);
        __syncthreads();
        if (!kg) {
            float4 p = *(const float4*)&wst[t8 * 4];
            float4 b = *(const float4*)&eb1[a * 128 + n4 * 4];
            hAT[(n4 * 4 + 0) * 14 + eE] = acc[0] + p.x + b.x;
            hAT[(n4 * 4 + 1) * 14 + eE] = acc[1] + p.y + b.y;
            hAT[(n4 * 4 + 2) * 14 + eE] = acc[2] + p.z + b.z;
            hAT[(n4 * 4 + 3) * 14 + eE] = acc[3] + p.w + b.w;
        }
    }
    __syncthreads();

    // selection layer 2: 128 -> 128, expert stream, K-split-2 (2x64)
    {
        const float* wb = ew2 + a * 16384;
        acc[0] = 0.f; acc[1] = 0.f; acc[2] = 0.f; acc[3] = 0.f;
        const int kb = kg * 64;
        for (int kk = 0; kk < 64; kk++) {
            int k = kb + kk;
            float4 w = *(const float4*)&wb[k * 128 + n4 * 4];
            float hv = hAT[k * 14 + eE];
            acc[0] = fmaf(hv, w.x, acc[0]); acc[1] = fmaf(hv, w.y, acc[1]);
            acc[2] = fmaf(hv, w.z, acc[2]); acc[3] = fmaf(hv, w.w, acc[3]);
        }
        __syncthreads();
        if (kg) *(float4*)&wst[t8 * 4] = make_float4(acc[0], acc[1], acc[2], acc[3]);
        __syncthreads();
        if (!kg) {
            float4 p = *(const float4*)&wst[t8 * 4];
            float4 b = *(const float4*)&eb2[a * 128 + n4 * 4];
            hBT[(n4 * 4 + 0) * 14 + eE] = acc[0] + p.x + b.x;
            hBT[(n4 * 4 + 1) * 14 + eE] = acc[1] + p.y + b.y;
            hBT[(n4 * 4 + 2) * 14 + eE] = acc[2] + p.z + b.z;
            hBT[(n4 * 4 + 3) * 14 + eE] = acc[3] + p.w + b.w;
        }
    }
    __syncthreads();

    // selection layer 3: 128 -> 10: 80 (e,o) pairs x 2 K-partials of 64
    if (tid < 160) {
        int pr = (tid >= 80) ? 1 : 0;
        int idx = tid - pr * 80;
        int e = idx / 10, o = idx - e * 10;
        int aa = acts[e];
        const float* w3 = &ew3[aa * 1280];
        float s = pr ? 0.f : eb3[aa * 10 + o];
        const int k0 = pr * 64;
        for (int k = k0; k < k0 + 64; k++) s = fmaf(hBT[k * 14 + e], w3[k * 10 + o], s);
        sp[tid] = s;
    }
    __syncthreads();
    if (tid < 80) {
        int e = tid / 10, o = tid - e * 10;
        out[(img0 + e) * 10 + o] = sp[tid] + sp[tid + 80];
    }
}

// ---------------------------------------------------------------------------
extern "C" void kernel_launch(void* const* d_in, const int* in_sizes, int n_in,
                              void* d_out, int out_size, void* d_ws, size_t ws_size,
                              hipStream_t stream)
{
    const float* x   = (const float*)d_in[0];
    const float* cw1 = (const float*)d_in[1];
    const float* cb1 = (const float*)d_in[2];
    const float* cw2 = (const float*)d_in[3];
    const float* cb2 = (const float*)d_in[4];
    const float* cw3 = (const float*)d_in[5];
    const float* cb3 = (const float*)d_in[6];
    const float* bng = (const float*)d_in[7];
    const float* bnb = (const float*)d_in[8];
    const float* pw1 = (const float*)d_in[9];
    const float* pb1 = (const float*)d_in[10];
    const float* pw2 = (const float*)d_in[11];
    const float* pb2 = (const float*)d_in[12];
    const float* pw3 = (const float*)d_in[13];
    const float* pb3 = (const float*)d_in[14];
    const float* ew1 = (const float*)d_in[15];
    const float* eb1 = (const float*)d_in[16];
    const float* ew2 = (const float*)d_in[17];
    const float* eb2 = (const float*)d_in[18];
    const float* ew3 = (const float*)d_in[19];
    const float* eb3 = (const float*)d_in[20];

    float* out     = (float*)d_out;
    float* out3    = (float*)d_ws;                    // 4096*288
    float* gstats  = out3 + 4096 * 288;               // 64 (atomic S/SS)
    float* packed2 = gstats + 64;                     // 9216
    float* packed3 = packed2 + 9216;                  // 9216

    hipMemsetAsync(gstats, 0, 64 * sizeof(float), stream);
    repack_kernel<<<72, 256, 0, stream>>>(cw2, cw3, packed2, packed3);
    fused_conv_kernel<<<4096, 256, 0, stream>>>(x, cw1, cb1, packed2, cb2,
                                                packed3, cb3, out3, gstats);
    mlp_select_kernel<<<512, 512, 0, stream>>>(out3, gstats, bng, bnb,
                                               pw1, pb1, pw2, pb2, pw3, pb3,
                                               ew1, eb1, ew2, eb2, ew3, eb3, out);
}

// Round 4
// 407.271 us; speedup vs baseline: 1.1744x; 1.1468x over previous
//
#include <hip/hip_runtime.h>

// ---------------------------------------------------------------------------
// Kernel 0: repack conv2/conv3 weights into [ic*9+tap][oc] linear layout.
// UNCHANGED.
// ---------------------------------------------------------------------------
__global__ __launch_bounds__(256) void repack_kernel(
    const float* __restrict__ cw2, const float* __restrict__ cw3,
    float* __restrict__ packed2, float* __restrict__ packed3)
{
    int t = blockIdx.x * 256 + threadIdx.x;   // grid 72*256 = 18432 = 2*9216
    if (t < 9216) {
        int oc = t & 31, r = t >> 5;          // r = ic*9+tap in [0,288)
        packed2[t] = cw2[oc * 288 + r];
    } else {
        int t2 = t - 9216;
        int oc = t2 & 31, r = t2 >> 5;
        packed3[t2] = cw3[oc * 288 + r];
    }
}

// ---------------------------------------------------------------------------
// Kernel 1: fused conv stack + fused BatchNorm partial-sum epilogue.
// conv1/conv2/pool/BN: UNCHANGED from r1 (the 313 us winner).
// conv3 NEW mapping (wave-uniform K-groups, compacted lanes):
//   wave0 = g0,u0..63 (full)   wave1 = g1,u0..63 (full)
//   wave2 = lanes 0..7: g0,u64..71 ; lanes 8..15: g1,u64..71 ; rest idle
//   wave3 = exec 0 -> execz-skips the whole conv3 compute stream.
// r3's lane-pair split is REVERTED: intra-wave ld variation made both
// ld-rows hit identical bank sets (stride 288 = 0 mod 32) -> 3x bank
// conflicts, 62% VALUBusy. Here g is wave-uniform for waves 0/1 (the bulk),
// mixed only across wave2's 16 lanes. K-reduction = r1 LDS scratch (same
// sum order -> bit-exact vs r1).
// ---------------------------------------------------------------------------
__global__ __launch_bounds__(256)
void fused_conv_kernel(
    const float* __restrict__ x,
    const float* __restrict__ cw1, const float* __restrict__ cb1,
    const float* __restrict__ packed2, const float* __restrict__ cb2,
    const float* __restrict__ packed3, const float* __restrict__ cb3,
    float* __restrict__ out3, float* __restrict__ gstats)
{
    const int img = blockIdx.x;
    const int tid = threadIdx.x;

    __shared__ float A[1220];         // xs1(900)+w1s(288)+b1s(32) | wck2(1152)
    __shared__ float B[8320];         // xs2 (32 x 260) | scratch/xs3/wck3
    __shared__ float b2s[32], b3s[32];

    float* xs1  = A;                  // 900: 30x30 padded image
    float* w1s  = A + 900;            // 288
    float* b1s  = A + 1188;           // 32
    float* wck2 = A;                  // 1152: conv2 4-ic chunk (after conv1)
    float* xs2  = B;                  // 32 planes x 260
    float* sc   = B;                  // reduction scratch head
    float* xs3  = B + 1280;           // 2880: 32 x 90 -> [1280,4160)
    float* wck3 = B + 4160;           // 2304: conv3 8-ic chunk -> [4160,6464)
    float* sc2  = B + 5073;           // pool scratch -> [5102,8320)

    // --- zero xs1 pads + all of B ---
    for (int i = tid; i < 900;  i += 256) xs1[i] = 0.f;
    for (int i = tid; i < 8320; i += 256) B[i] = 0.f;
    __syncthreads();

    // --- stage input image + conv1 weights + biases ---
    for (int i = tid; i < 784; i += 256) {
        int yy = i / 28, xx = i % 28;
        xs1[(yy + 1) * 30 + xx + 1] = x[img * 784 + i];
    }
    for (int i = tid; i < 288; i += 256) {
        int oc = i & 31, tap = i >> 5;
        w1s[i] = cw1[oc * 9 + tap];
    }
    if (tid < 32) { b1s[tid] = cb1[tid]; b2s[tid] = cb2[tid]; b3s[tid] = cb3[tid]; }
    __syncthreads();

    // --- conv1 (1->32) + relu + pool -> xs2 (swizzled) ---
    {
        const int c1 = tid & 31;
        float w1r[9];
        #pragma unroll
        for (int t = 0; t < 9; t++) w1r[t] = w1s[t * 32 + c1];
        const float bias1 = b1s[c1];
        for (int o = tid; o < 32 * 196; o += 256) {
            int p = o >> 5;
            int py = p / 14, px = p % 14;
            int base = (2 * py) * 30 + 2 * px;
            float P[16];
            #pragma unroll
            for (int r = 0; r < 4; r++) {
                float2 u0 = *(const float2*)&xs1[base + r * 30];
                float2 u1 = *(const float2*)&xs1[base + r * 30 + 2];
                P[r * 4 + 0] = u0.x; P[r * 4 + 1] = u0.y;
                P[r * 4 + 2] = u1.x; P[r * 4 + 3] = u1.y;
            }
            float a00 = 0.f, a01 = 0.f, a10 = 0.f, a11 = 0.f;
            #pragma unroll
            for (int ky = 0; ky < 3; ky++)
                #pragma unroll
                for (int kx = 0; kx < 3; kx++) {
                    float w = w1r[ky * 3 + kx];
                    a00 = fmaf(P[ky * 4 + kx],           w, a00);
                    a01 = fmaf(P[ky * 4 + kx + 1],       w, a01);
                    a10 = fmaf(P[(ky + 1) * 4 + kx],     w, a10);
                    a11 = fmaf(P[(ky + 1) * 4 + kx + 1], w, a11);
                }
            float v = fmaxf(fmaxf(fmaxf(a00, a01), fmaxf(a10, a11)) + bias1, 0.f);
            int r = py + 1, col = px + 1;
            xs2[c1 * 260 + r * 16 + ((((col >> 2) + r) & 3) << 2) + (col & 3)] = v;
        }
    }

    // --- conv2: 4oc x 14 cols, K-split-2 over 8 chunks of 4 ic ---
    const int g  = tid >> 7;            // K-group 0..1 (2 waves each)
    const int u  = tid & 127;           // unit; active if u < 112
    const int cb = u & 7, R = u >> 3;   // oc-quad, prepool row 0..13
    const int oc0 = cb * 4;
    const bool act2 = (u < 112);

    float acc[4][14];
    #pragma unroll
    for (int a = 0; a < 4; a++)
        #pragma unroll
        for (int c = 0; c < 14; c++) acc[a][c] = 0.f;

    float pf[5];                        // 1152 = 4.5*256
    #pragma unroll
    for (int k = 0; k < 5; k++) {
        int idx = tid + k * 256;
        pf[k] = (idx < 1152) ? packed2[idx] : 0.f;
    }

    for (int ch = 0; ch < 8; ch++) {
        __syncthreads();                // conv1/xs2 writes + prior wck2 reads done
        #pragma unroll
        for (int k = 0; k < 5; k++) {
            int idx = tid + k * 256;
            if (idx < 1152) wck2[idx] = pf[k];
        }
        if (ch < 7) {
            #pragma unroll
            for (int k = 0; k < 5; k++) {
                int idx = tid + k * 256;
                pf[k] = (idx < 1152) ? packed2[(ch + 1) * 1152 + idx] : 0.f;
            }
        }
        __syncthreads();
        if (act2) {
            #pragma unroll
            for (int d = 0; d < 2; d++) {
                const int ld = g * 2 + d;            // local ic 0..3
                const int ic = ch * 4 + ld;
                const float* wd = &wck2[ld * 288 + oc0];
                const int pb = ic * 260;
                #pragma unroll
                for (int ky = 0; ky < 3; ky++) {
                    const int rp = R + ky;
                    const int rb = pb + rp * 16;
                    float row[16];
                    #pragma unroll
                    for (int q = 0; q < 4; q++) {
                        const float4 t = *(const float4*)&xs2[rb + (((q + rp) & 3) << 2)];
                        row[q * 4 + 0] = t.x; row[q * 4 + 1] = t.y;
                        row[q * 4 + 2] = t.z; row[q * 4 + 3] = t.w;
                    }
                    const float4 wa = *(const float4*)&wd[(ky * 3 + 0) * 32];
                    const float4 wb = *(const float4*)&wd[(ky * 3 + 1) * 32];
                    const float4 wc = *(const float4*)&wd[(ky * 3 + 2) * 32];
                    #pragma unroll
                    for (int c = 0; c < 14; c++) {
                        acc[0][c] = fmaf(row[c],     wa.x, acc[0][c]);
                        acc[1][c] = fmaf(row[c],     wa.y, acc[1][c]);
                        acc[2][c] = fmaf(row[c],     wa.z, acc[2][c]);
                        acc[3][c] = fmaf(row[c],     wa.w, acc[3][c]);
                        acc[0][c] = fmaf(row[c + 1], wb.x, acc[0][c]);
                        acc[1][c] = fmaf(row[c + 1], wb.y, acc[1][c]);
                        acc[2][c] = fmaf(row[c + 1], wb.z, acc[2][c]);
                        acc[3][c] = fmaf(row[c + 1], wb.w, acc[3][c]);
                        acc[0][c] = fmaf(row[c + 2], wc.x, acc[0][c]);
                        acc[1][c] = fmaf(row[c + 2], wc.y, acc[1][c]);
                        acc[2][c] = fmaf(row[c + 2], wc.z, acc[2][c]);
                        acc[3][c] = fmaf(row[c + 2], wc.w, acc[3][c]);
                    }
                }
            }
        }
    }

    // --- conv2 K-reduction (1 round, stride-57 scratch in B head, max 6382) ---
    __syncthreads();                     // all xs2 patch reads done
    if (g == 1 && act2) {
        #pragma unroll
        for (int a = 0; a < 4; a++)
            #pragma unroll
            for (int c = 0; c < 14; c++) sc[u * 57 + a * 14 + c] = acc[a][c];
    }
    __syncthreads();
    if (g == 0 && act2) {
        #pragma unroll
        for (int a = 0; a < 4; a++)
            #pragma unroll
            for (int c = 0; c < 14; c++) acc[a][c] += sc[u * 57 + a * 14 + c];
    }
    __syncthreads();                     // reduction scratch retires

    // --- zero xs3 + pool 14x14->7x7 (register hmax, odd/even R via sc2) ---
    for (int i = tid; i < 2880; i += 256) xs3[i] = 0.f;
    float hm[4][7];
    if (g == 0 && act2) {
        #pragma unroll
        for (int a = 0; a < 4; a++)
            #pragma unroll
            for (int c = 0; c < 7; c++)
                hm[a][c] = fmaxf(acc[a][2 * c], acc[a][2 * c + 1]);
        if (R & 1) {                     // sc2 idx max 111*29+27=3246 -> abs 8319
            #pragma unroll
            for (int a = 0; a < 4; a++)
                #pragma unroll
                for (int c = 0; c < 7; c++) sc2[u * 29 + a * 7 + c] = hm[a][c];
        }
    }
    __syncthreads();
    if (g == 0 && act2 && !(R & 1)) {
        const int py = R >> 1;           // 0..6
        #pragma unroll
        for (int a = 0; a < 4; a++)
            #pragma unroll
            for (int c = 0; c < 7; c++) {
                float v = fmaxf(hm[a][c], sc2[(u + 8) * 29 + a * 7 + c]);
                v = fmaxf(v + b2s[oc0 + a], 0.f);
                xs3[(oc0 + a) * 90 + (py + 1) * 10 + (c + 1)] = v;
            }
    }

    // --- conv3 (32->32, 7x7) + relu + pool(7->3 floor), compacted K-split ---
    // wave0: g0,u0..63  wave1: g1,u0..63  wave2: 16 lanes for u64..71 (both g)
    // wave3: fully inactive (execz skip).
    const int w3v = tid >> 6;            // wave id 0..3
    const int l3  = tid & 63;            // lane
    int g3, u3;
    bool act3;
    if (w3v < 2)      { g3 = w3v;       u3 = l3;            act3 = true;      }
    else if (w3v == 2){ g3 = (l3 >= 8); u3 = 64 + (l3 & 7); act3 = (l3 < 16); }
    else              { g3 = 0;         u3 = 0;             act3 = false;     }
    const int cq3 = u3 & 7, pos = u3 >> 3;   // oc-quad, pooled pos 0..8
    const int oc30 = cq3 * 4;
    const int py3 = pos / 3, px3 = pos % 3;
    const int base3 = (2 * py3) * 10 + 2 * px3;

    float a3[4][4];
    #pragma unroll
    for (int a = 0; a < 4; a++)
        #pragma unroll
        for (int q = 0; q < 4; q++) a3[a][q] = 0.f;

    float pg[9];                        // 2304 = 9*256
    #pragma unroll
    for (int k = 0; k < 9; k++) pg[k] = packed3[tid + k * 256];

    for (int ch = 0; ch < 4; ch++) {
        __syncthreads();                 // pool/xs3 writes + prior wck3 reads done
        #pragma unroll
        for (int k = 0; k < 9; k++) wck3[tid + k * 256] = pg[k];
        if (ch < 3) {
            #pragma unroll
            for (int k = 0; k < 9; k++) pg[k] = packed3[(ch + 1) * 2304 + tid + k * 256];
        }
        __syncthreads();
        if (act3) {
            #pragma unroll 2
            for (int d = 0; d < 4; d++) {
                const int ld = g3 * 4 + d;
                const int ic = ch * 8 + ld;
                const float* xp = &xs3[ic * 90 + base3];
                float P[16];
                #pragma unroll
                for (int r = 0; r < 4; r++) {
                    float2 u0 = *(const float2*)&xp[r * 10];
                    float2 u1 = *(const float2*)&xp[r * 10 + 2];
                    P[r * 4 + 0] = u0.x; P[r * 4 + 1] = u0.y;
                    P[r * 4 + 2] = u1.x; P[r * 4 + 3] = u1.y;
                }
                const float* wd = &wck3[ld * 288 + oc30];
                #pragma unroll
                for (int tap = 0; tap < 9; tap++) {
                    const int ky = tap / 3, kx = tap % 3;
                    const float4 wv = *(const float4*)&wd[tap * 32];
                    const float x00 = P[ky * 4 + kx];
                    const float x01 = P[ky * 4 + kx + 1];
                    const float x10 = P[(ky + 1) * 4 + kx];
                    const float x11 = P[(ky + 1) * 4 + kx + 1];
                    a3[0][0] = fmaf(x00, wv.x, a3[0][0]); a3[0][1] = fmaf(x01, wv.x, a3[0][1]);
                    a3[0][2] = fmaf(x10, wv.x, a3[0][2]); a3[0][3] = fmaf(x11, wv.x, a3[0][3]);
                    a3[1][0] = fmaf(x00, wv.y, a3[1][0]); a3[1][1] = fmaf(x01, wv.y, a3[1][1]);
                    a3[1][2] = fmaf(x10, wv.y, a3[1][2]); a3[1][3] = fmaf(x11, wv.y, a3[1][3]);
                    a3[2][0] = fmaf(x00, wv.z, a3[2][0]); a3[2][1] = fmaf(x01, wv.z, a3[2][1]);
                    a3[2][2] = fmaf(x10, wv.z, a3[2][2]); a3[2][3] = fmaf(x11, wv.z, a3[2][3]);
                    a3[3][0] = fmaf(x00, wv.w, a3[3][0]); a3[3][1] = fmaf(x01, wv.w, a3[3][1]);
                    a3[3][2] = fmaf(x10, wv.w, a3[3][2]); a3[3][3] = fmaf(x11, wv.w, a3[3][3]);
                }
            }
        }
    }

    // --- conv3 K-reduction (1 round, stride-17 scratch in head, max 1222) ---
    __syncthreads();
    if (g3 == 1 && act3) {
        #pragma unroll
        for (int a = 0; a < 4; a++)
            #pragma unroll
            for (int q = 0; q < 4; q++) sc[u3 * 17 + a * 4 + q] = a3[a][q];
    }
    __syncthreads();
    float rres[4];
    const bool writer = (g3 == 0 && act3);
    if (writer) {
        #pragma unroll
        for (int a = 0; a < 4; a++)
            #pragma unroll
            for (int q = 0; q < 4; q++) a3[a][q] += sc[u3 * 17 + a * 4 + q];
        float4 res;
        #pragma unroll
        for (int a = 0; a < 4; a++) {
            float v = fmaxf(fmaxf(a3[a][0], a3[a][1]), fmaxf(a3[a][2], a3[a][3]));
            rres[a] = fmaxf(v + b3s[oc30 + a], 0.f);
        }
        res.x = rres[0]; res.y = rres[1]; res.z = rres[2]; res.w = rres[3];
        *(float4*)&out3[img * 288 + pos * 32 + oc30] = res;
    }

    // --- fused BN partial sums: single-writer LDS grid then 64 atomics ---
    __syncthreads();                     // sc reads done -> B reusable
    for (int i = tid; i < 576; i += 256) B[i] = 0.f;
    __syncthreads();
    if (writer) {
        #pragma unroll
        for (int a = 0; a < 4; a++) {
            B[pos * 64 + oc30 + a]      = rres[a];
            B[pos * 64 + 32 + oc30 + a] = rres[a] * rres[a];
        }
    }
    __syncthreads();
    if (tid < 64) {
        int c = tid & 31, part = tid >> 5;   // part 0 = S, 1 = SS
        float s = 0.f;
        #pragma unroll
        for (int p = 0; p < 9; p++) s += B[p * 64 + part * 32 + c];
        atomicAdd(&gstats[part * 32 + c], s);
    }
}

// ---------------------------------------------------------------------------
// Kernel 3: BN-finalize + BN-apply + MLP + argmax + 3 selection layers.
// r1 version UNCHANGED (measured best: ~96 us tail). 512-thread blocks,
// K-split-2 on every layer; MLP weights staged through LDS; selection
// layers keep direct per-half-wave expert streams.
// ---------------------------------------------------------------------------
__global__ __launch_bounds__(512) void mlp_select_kernel(
    const float* __restrict__ out3, const float* __restrict__ gstats,
    const float* __restrict__ bng, const float* __restrict__ bnb,
    const float* __restrict__ pw1, const float* __restrict__ pb1,
    const float* __restrict__ pw2, const float* __restrict__ pb2,
    const float* __restrict__ pw3, const float* __restrict__ pb3,
    const float* __restrict__ ew1, const float* __restrict__ eb1,
    const float* __restrict__ ew2, const float* __restrict__ eb2,
    const float* __restrict__ ew3, const float* __restrict__ eb3,
    float* __restrict__ out)
{
    const int tid = threadIdx.x;          // 0..511
    const int img0 = blockIdx.x * 8;

    __shared__ float ysT[288 * 14];       // [j][e], stride 14
    __shared__ float hAT[128 * 14];
    __shared__ float hBT[128 * 14];
    __shared__ float wst[32 * 128];       // staged weight tile / K-reduce scratch
    __shared__ float lgp[48];
    __shared__ float sp[160];
    __shared__ int   acts[8];
    __shared__ float sa[32], sb[32];

    // BN finalize from global atomic sums (redundant per block; ~free)
    if (tid < 32) {
        float S = gstats[tid], SS = gstats[32 + tid];
        const float inv_n = 1.f / (4096.f * 9.f);
        float mean = S * inv_n;
        float var = SS * inv_n - mean * mean;
        float a = bng[tid] * rsqrtf(var + 1e-5f);
        sa[tid] = a;
        sb[tid] = bnb[tid] - a * mean;
    }
    __syncthreads();

    // stage + BN: 8*72 = 576 float4 reads, scatter-transpose into ysT
    for (int it = 0; it < 2; it++) {
        int i4 = it * 512 + tid;
        if (i4 < 576) {
            int e = i4 / 72, jq = i4 - e * 72;
            float4 v = *(const float4*)&out3[(img0 + e) * 288 + jq * 4];
            int j = jq * 4;
            ysT[(j + 0) * 14 + e] = fmaf(sa[(j + 0) & 31], v.x, sb[(j + 0) & 31]);
            ysT[(j + 1) * 14 + e] = fmaf(sa[(j + 1) & 31], v.y, sb[(j + 1) & 31]);
            ysT[(j + 2) * 14 + e] = fmaf(sa[(j + 2) & 31], v.z, sb[(j + 2) & 31]);
            ysT[(j + 3) * 14 + e] = fmaf(sa[(j + 3) & 31], v.w, sb[(j + 3) & 31]);
        }
    }

    const int kg = tid >> 8;              // K-half 0/1 (4 waves each)
    const int t8 = tid & 255;
    const int n4 = t8 & 31;               // neuron quad: n = n4*4 .. n4*4+3
    const int eE = t8 >> 5;               // example 0..7 (half-wave uniform)
    const int j0 = kg * 16;               // per-tile j-half for staged layers
    float acc[4];

    // layer 1: 288 -> 128, relu — K tiled by 32 (staged in wst), K-split-2
    {
        acc[0] = 0.f; acc[1] = 0.f; acc[2] = 0.f; acc[3] = 0.f;
        for (int t = 0; t < 9; t++) {
            __syncthreads();              // first iter also covers ysT staging
            #pragma unroll
            for (int s = 0; s < 2; s++) {
                int idx = s * 512 + tid;  // 1024 float4 slots
                int row = idx >> 5, c4 = idx & 31;
                int k = t * 32 + row;
                int i = (k & 31) * 9 + (k >> 5);
                *(float4*)&wst[row * 128 + c4 * 4] =
                    *(const float4*)&pw1[i * 128 + c4 * 4];
            }
            __syncthreads();
            #pragma unroll
            for (int j = 0; j < 16; j++) {
                float4 w = *(const float4*)&wst[(j0 + j) * 128 + n4 * 4];
                float yv = ysT[(t * 32 + j0 + j) * 14 + eE];
                acc[0] = fmaf(yv, w.x, acc[0]); acc[1] = fmaf(yv, w.y, acc[1]);
                acc[2] = fmaf(yv, w.z, acc[2]); acc[3] = fmaf(yv, w.w, acc[3]);
            }
        }
        __syncthreads();                  // last tile reads done -> wst reusable
        if (kg) *(float4*)&wst[t8 * 4] = make_float4(acc[0], acc[1], acc[2], acc[3]);
        __syncthreads();
        if (!kg) {
            float4 p = *(const float4*)&wst[t8 * 4];
            float4 b = *(const float4*)&pb1[n4 * 4];
            hAT[(n4 * 4 + 0) * 14 + eE] = fmaxf(acc[0] + p.x + b.x, 0.f);
            hAT[(n4 * 4 + 1) * 14 + eE] = fmaxf(acc[1] + p.y + b.y, 0.f);
            hAT[(n4 * 4 + 2) * 14 + eE] = fmaxf(acc[2] + p.z + b.z, 0.f);
            hAT[(n4 * 4 + 3) * 14 + eE] = fmaxf(acc[3] + p.w + b.w, 0.f);
        }
    }

    // layer 2: 128 -> 128, relu — staged tiles, K-split-2
    {
        acc[0] = 0.f; acc[1] = 0.f; acc[2] = 0.f; acc[3] = 0.f;
        for (int t = 0; t < 4; t++) {
            __syncthreads();              // hAT writes + prior wst reads done
            #pragma unroll
            for (int s = 0; s < 2; s++) {
                int idx = s * 512 + tid;
                int row = idx >> 5, c4 = idx & 31;
                int k = t * 32 + row;
                *(float4*)&wst[row * 128 + c4 * 4] =
                    *(const float4*)&pw2[k * 128 + c4 * 4];
            }
            __syncthreads();
            #pragma unroll
            for (int j = 0; j < 16; j++) {
                float4 w = *(const float4*)&wst[(j0 + j) * 128 + n4 * 4];
                float hv = hAT[(t * 32 + j0 + j) * 14 + eE];
                acc[0] = fmaf(hv, w.x, acc[0]); acc[1] = fmaf(hv, w.y, acc[1]);
                acc[2] = fmaf(hv, w.z, acc[2]); acc[3] = fmaf(hv, w.w, acc[3]);
            }
        }
        __syncthreads();
        if (kg) *(float4*)&wst[t8 * 4] = make_float4(acc[0], acc[1], acc[2], acc[3]);
        __syncthreads();
        if (!kg) {
            float4 p = *(const float4*)&wst[t8 * 4];
            float4 b = *(const float4*)&pb2[n4 * 4];
            hBT[(n4 * 4 + 0) * 14 + eE] = fmaxf(acc[0] + p.x + b.x, 0.f);
            hBT[(n4 * 4 + 1) * 14 + eE] = fmaxf(acc[1] + p.y + b.y, 0.f);
            hBT[(n4 * 4 + 2) * 14 + eE] = fmaxf(acc[2] + p.z + b.z, 0.f);
            hBT[(n4 * 4 + 3) * 14 + eE] = fmaxf(acc[3] + p.w + b.w, 0.f);
        }
    }
    __syncthreads();

    // logits 128 -> 3: 24 (e,o) pairs x 2 K-partials of 64 (UNCHANGED order)
    if (tid < 48) {
        int pr = tid & 1, eo = tid >> 1;
        int e = eo / 3, o = eo - e * 3;
        float s = pr ? 0.f : pb3[o];
        const int k0 = pr * 64;
        for (int k = k0; k < k0 + 64; k++) s = fmaf(hBT[k * 14 + e], pw3[k * 3 + o], s);
        lgp[tid] = s;
    }
    __syncthreads();
    if (tid < 8) {
        float l0 = lgp[(tid * 3 + 0) * 2] + lgp[(tid * 3 + 0) * 2 + 1];
        float l1 = lgp[(tid * 3 + 1) * 2] + lgp[(tid * 3 + 1) * 2 + 1];
        float l2 = lgp[(tid * 3 + 2) * 2] + lgp[(tid * 3 + 2) * 2 + 1];
        int a = 0; float best = l0;
        if (l1 > best) { best = l1; a = 1; }
        if (l2 > best) { best = l2; a = 2; }
        acts[tid] = a;
        out[4096 * 10 + img0 + tid] = (float)a;
    }
    __syncthreads();

    const int a = acts[eE];               // half-wave-uniform expert id

    // selection layer 1: 288 -> 128, expert stream, K-split-2 (2x144)
    {
        const float* wb = ew1 + a * 36864;
        acc[0] = 0.f; acc[1] = 0.f; acc[2] = 0.f; acc[3] = 0.f;
        const int kb = kg * 144;
        for (int kk = 0; kk < 144; kk++) {
            int k = kb + kk;
            int i = (k & 31) * 9 + (k >> 5);
            float4 w = *(const float4*)&wb[i * 128 + n4 * 4];
            float yv = ysT[k * 14 + eE];
            acc[0] = fmaf(yv, w.x, acc[0]); acc[1] = fmaf(yv, w.y, acc[1]);
            acc[2] = fmaf(yv, w.z, acc[2]); acc[3] = fmaf(yv, w.w, acc[3]);
        }
        __syncthreads();                  // logits-phase hBT reads done; wst free
        if (kg) *(float4*)&wst[t8 * 4] = make_float4(acc[0], acc[1], acc[2], acc[3]);
        __syncthreads();
        if (!kg) {
            float4 p = *(const float4*)&wst[t8 * 4];
            float4 b = *(const float4*)&eb1[a * 128 + n4 * 4];
            hAT[(n4 * 4 + 0) * 14 + eE] = acc[0] + p.x + b.x;
            hAT[(n4 * 4 + 1) * 14 + eE] = acc[1] + p.y + b.y;
            hAT[(n4 * 4 + 2) * 14 + eE] = acc[2] + p.z + b.z;
            hAT[(n4 * 4 + 3) * 14 + eE] = acc[3] + p.w + b.w;
        }
    }
    __syncthreads();

    // selection layer 2: 128 -> 128, expert stream, K-split-2 (2x64)
    {
        const float* wb = ew2 + a * 16384;
        acc[0] = 0.f; acc[1] = 0.f; acc[2] = 0.f; acc[3] = 0.f;
        const int kb = kg * 64;
        for (int kk = 0; kk < 64; kk++) {
            int k = kb + kk;
            float4 w = *(const float4*)&wb[k * 128 + n4 * 4];
            float hv = hAT[k * 14 + eE];
            acc[0] = fmaf(hv, w.x, acc[0]); acc[1] = fmaf(hv, w.y, acc[1]);
            acc[2] = fmaf(hv, w.z, acc[2]); acc[3] = fmaf(hv, w.w, acc[3]);
        }
        __syncthreads();
        if (kg) *(float4*)&wst[t8 * 4] = make_float4(acc[0], acc[1], acc[2], acc[3]);
        __syncthreads();
        if (!kg) {
            float4 p = *(const float4*)&wst[t8 * 4];
            float4 b = *(const float4*)&eb2[a * 128 + n4 * 4];
            hBT[(n4 * 4 + 0) * 14 + eE] = acc[0] + p.x + b.x;
            hBT[(n4 * 4 + 1) * 14 + eE] = acc[1] + p.y + b.y;
            hBT[(n4 * 4 + 2) * 14 + eE] = acc[2] + p.z + b.z;
            hBT[(n4 * 4 + 3) * 14 + eE] = acc[3] + p.w + b.w;
        }
    }
    __syncthreads();

    // selection layer 3: 128 -> 10: 80 (e,o) pairs x 2 K-partials of 64
    if (tid < 160) {
        int pr = (tid >= 80) ? 1 : 0;
        int idx = tid - pr * 80;
        int e = idx / 10, o = idx - e * 10;
        int aa = acts[e];
        const float* w3 = &ew3[aa * 1280];
        float s = pr ? 0.f : eb3[aa * 10 + o];
        const int k0 = pr * 64;
        for (int k = k0; k < k0 + 64; k++) s = fmaf(hBT[k * 14 + e], w3[k * 10 + o], s);
        sp[tid] = s;
    }
    __syncthreads();
    if (tid < 80) {
        int e = tid / 10, o = tid - e * 10;
        out[(img0 + e) * 10 + o] = sp[tid] + sp[tid + 80];
    }
}

// ---------------------------------------------------------------------------
extern "C" void kernel_launch(void* const* d_in, const int* in_sizes, int n_in,
                              void* d_out, int out_size, void* d_ws, size_t ws_size,
                              hipStream_t stream)
{
    const float* x   = (const float*)d_in[0];
    const float* cw1 = (const float*)d_in[1];
    const float* cb1 = (const float*)d_in[2];
    const float* cw2 = (const float*)d_in[3];
    const float* cb2 = (const float*)d_in[4];
    const float* cw3 = (const float*)d_in[5];
    const float* cb3 = (const float*)d_in[6];
    const float* bng = (const float*)d_in[7];
    const float* bnb = (const float*)d_in[8];
    const float* pw1 = (const float*)d_in[9];
    const float* pb1 = (const float*)d_in[10];
    const float* pw2 = (const float*)d_in[11];
    const float* pb2 = (const float*)d_in[12];
    const float* pw3 = (const float*)d_in[13];
    const float* pb3 = (const float*)d_in[14];
    const float* ew1 = (const float*)d_in[15];
    const float* eb1 = (const float*)d_in[16];
    const float* ew2 = (const float*)d_in[17];
    const float* eb2 = (const float*)d_in[18];
    const float* ew3 = (const float*)d_in[19];
    const float* eb3 = (const float*)d_in[20];

    float* out     = (float*)d_out;
    float* out3    = (float*)d_ws;                    // 4096*288
    float* gstats  = out3 + 4096 * 288;               // 64 (atomic S/SS)
    float* packed2 = gstats + 64;                     // 9216
    float* packed3 = packed2 + 9216;                  // 9216

    hipMemsetAsync(gstats, 0, 64 * sizeof(float), stream);
    repack_kernel<<<72, 256, 0, stream>>>(cw2, cw3, packed2, packed3);
    fused_conv_kernel<<<4096, 256, 0, stream>>>(x, cw1, cb1, packed2, cb2,
                                                packed3, cb3, out3, gstats);
    mlp_select_kernel<<<512, 512, 0, stream>>>(out3, gstats, bng, bnb,
                                               pw1, pb1, pw2, pb2, pw3, pb3,
                                               ew1, eb1, ew2, eb2, ew3, eb3, out);
}